// Round 4
// baseline (2553.761 us; speedup 1.0000x reference)
//
#include <hip/hip_runtime.h>
#include <hip/hip_fp16.h>

#define NNODES 50000
#define NEDGES 800000
#define IN_F   256
#define HID_F  128
#define OUT_F  16
#define HOPS   30

typedef unsigned int u32;
typedef u32 u32x4 __attribute__((ext_vector_type(4)));
typedef unsigned long long u64;

union U32H2 { u32 u; __half2 h; };

__device__ inline float2 upk(u32 v) {
    U32H2 t; t.u = v;
    return __half22float2(t.h);
}
__device__ inline u32 pk2(float a, float b) {
    U32H2 t; t.h = __floats2half2_rn(a, b);
    return t.u;
}

// ---------------- graph setup kernels ----------------

__global__ void k_init_deg(int* __restrict__ deg, int n) {
    int i = blockIdx.x * blockDim.x + threadIdx.x;
    if (i < n) deg[i] = 1;  // self-loop
}

__global__ void k_count(const int* __restrict__ dst, int* __restrict__ deg, int e) {
    int i = blockIdx.x * blockDim.x + threadIdx.x;
    if (i < e) atomicAdd(&deg[dst[i]], 1);
}

__global__ void k_dinv(const int* __restrict__ deg, float* __restrict__ dinv, int n) {
    int i = blockIdx.x * blockDim.x + threadIdx.x;
    if (i < n) dinv[i] = rsqrtf((float)deg[i]);
}

__global__ void k_scan1(const int* __restrict__ deg, int* __restrict__ bsums, int n) {
    __shared__ int sh[256];
    int tid = threadIdx.x;
    int i = blockIdx.x * 256 + tid;
    sh[tid] = (i < n) ? deg[i] : 0;
    __syncthreads();
    for (int ofs = 128; ofs > 0; ofs >>= 1) {
        if (tid < ofs) sh[tid] += sh[tid + ofs];
        __syncthreads();
    }
    if (tid == 0) bsums[blockIdx.x] = sh[0];
}

__global__ void k_scan2(int* __restrict__ bsums, int nb, int* __restrict__ rp, int n) {
    if (threadIdx.x == 0 && blockIdx.x == 0) {
        int run = 0;
        for (int b = 0; b < nb; ++b) { int t = bsums[b]; bsums[b] = run; run += t; }
        rp[n] = run;
    }
}

__global__ void k_scan3(const int* __restrict__ deg, const int* __restrict__ bsums,
                        int* __restrict__ rp, int* __restrict__ cursor, int n) {
    __shared__ int sh[256];
    int tid = threadIdx.x;
    int i = blockIdx.x * 256 + tid;
    int v = (i < n) ? deg[i] : 0;
    sh[tid] = v;
    __syncthreads();
    for (int ofs = 1; ofs < 256; ofs <<= 1) {
        int t = 0;
        if (tid >= ofs) t = sh[tid - ofs];
        __syncthreads();
        sh[tid] += t;
        __syncthreads();
    }
    if (i < n) {
        int excl = sh[tid] - v + bsums[blockIdx.x];
        rp[i] = excl;
        cursor[i] = excl;
    }
}

// packed edge: .x = src node, .y = bits of edge weight
__global__ void k_scatter(const int* __restrict__ src, const int* __restrict__ dst,
                          const float* __restrict__ dinv, int* __restrict__ cursor,
                          int2* __restrict__ ew, int e, int n) {
    int t = blockIdx.x * blockDim.x + threadIdx.x;
    if (t < e) {
        int s = src[t], d = dst[t];
        int pos = atomicAdd(&cursor[d], 1);
        ew[pos] = make_int2(s, __float_as_int(dinv[s] * dinv[d]));
    } else if (t < e + n) {
        int i = t - e;
        int pos = atomicAdd(&cursor[i], 1);
        float di = dinv[i];
        ew[pos] = make_int2(i, __float_as_int(di * di));
    }
}

// ------------- GEMM: C[M,128] = (relu?)(A[M,K] @ W[K,128] + b) -------------
// 32-row x 128-col tile, 256 threads, each thread 4 rows x 4 cols.

template<int K, bool RELU, bool HALF_OUT>
__global__ void k_gemm32(const float* __restrict__ A, const float* __restrict__ W,
                         const float* __restrict__ b, void* __restrict__ C, int M) {
    __shared__ float sa[32][K];
    int tid  = threadIdx.x;
    int row0 = blockIdx.x * 32;
    constexpr int KV = K / 4;

    const float4* A4 = reinterpret_cast<const float4*>(A);
    for (int idx = tid; idx < 32 * KV; idx += 256) {
        int r  = idx / KV;
        int c4 = idx % KV;
        int gr = row0 + r;
        float4 v = (gr < M) ? A4[(size_t)gr * KV + c4]
                            : make_float4(0.f, 0.f, 0.f, 0.f);
        *reinterpret_cast<float4*>(&sa[r][c4 * 4]) = v;
    }
    __syncthreads();

    int tc = tid & 31;   // cols 4*tc .. 4*tc+3
    int tr = tid >> 5;   // rows 4*tr .. 4*tr+3
    float4 acc[4];
#pragma unroll
    for (int j = 0; j < 4; ++j) acc[j] = make_float4(0.f, 0.f, 0.f, 0.f);

    const float4* W4 = reinterpret_cast<const float4*>(W);
#pragma unroll 2
    for (int k4 = 0; k4 < KV; ++k4) {
        float4 a[4];
#pragma unroll
        for (int j = 0; j < 4; ++j)
            a[j] = *reinterpret_cast<const float4*>(&sa[tr * 4 + j][k4 * 4]);
        const float* af = reinterpret_cast<const float*>(a);
#pragma unroll
        for (int kk = 0; kk < 4; ++kk) {
            float4 wv = W4[(size_t)(k4 * 4 + kk) * 32 + tc];
#pragma unroll
            for (int j = 0; j < 4; ++j) {
                float av = af[j * 4 + kk];
                acc[j].x += av * wv.x; acc[j].y += av * wv.y;
                acc[j].z += av * wv.z; acc[j].w += av * wv.w;
            }
        }
    }

    float4 bb = reinterpret_cast<const float4*>(b)[tc];
#pragma unroll
    for (int j = 0; j < 4; ++j) {
        int r = row0 + tr * 4 + j;
        if (r < M) {
            float4 v;
            v.x = acc[j].x + bb.x; v.y = acc[j].y + bb.y;
            v.z = acc[j].z + bb.z; v.w = acc[j].w + bb.w;
            if (RELU) {
                v.x = fmaxf(v.x, 0.f); v.y = fmaxf(v.y, 0.f);
                v.z = fmaxf(v.z, 0.f); v.w = fmaxf(v.w, 0.f);
            }
            if (HALF_OUT) {
                u32 lo = pk2(v.x, v.y), hi = pk2(v.z, v.w);
                reinterpret_cast<uint2*>(C)[(size_t)r * 32 + tc] = make_uint2(lo, hi);
            } else {
                reinterpret_cast<float4*>(C)[(size_t)r * 32 + tc] = v;
            }
        }
    }
}

// ---- propagation at width 128, fp16, 4-chunk XCD-affine ----
// chunk = blockIdx&3 (XCD c and c+4 share chunk c&3): 32 features = 64B/row
// -> slice 3.2MB fits a 4MB per-XCD L2. Edge stream + output use
// non-temporal hints so the resident slice isn't evicted.
// 4 lanes per node (one u32x4 = 8 halves each), 64 nodes per block.

template<bool RELU>
__global__ void k_proph4(const u32* __restrict__ Hin, u32* __restrict__ Hout,
                         const int* __restrict__ rp, const int2* __restrict__ ew,
                         int n) {
    int chunk = blockIdx.x & 3;
    int tile  = blockIdx.x >> 2;
    int grp   = threadIdx.x >> 2;   // 64 nodes per block
    int lane  = threadIdx.x & 3;
    int node  = tile * 64 + grp;
    if (node >= n) return;
    int beg = rp[node], end = rp[node + 1];
    const u32x4* H4 = reinterpret_cast<const u32x4*>(Hin);   // row = 16 u32x4
    const u64* ew8  = reinterpret_cast<const u64*>(ew);
    int off = chunk * 4 + lane;

    float acc[8];
#pragma unroll
    for (int i = 0; i < 8; ++i) acc[i] = 0.f;

    auto body = [&](int e) {
        u64 pw   = __builtin_nontemporal_load(ew8 + e);
        int s    = (int)(u32)pw;
        float ww = __int_as_float((u32)(pw >> 32));
        u32x4 v  = H4[(size_t)s * 16 + off];
#pragma unroll
        for (int q = 0; q < 4; ++q) {
            float2 f = upk(v[q]);
            acc[q * 2 + 0] += ww * f.x;
            acc[q * 2 + 1] += ww * f.y;
        }
    };

    int e = beg;
    for (; e + 1 < end; e += 2) { body(e); body(e + 1); }
    if (e < end) body(e);

    if (RELU) {
#pragma unroll
        for (int i = 0; i < 8; ++i) acc[i] = fmaxf(acc[i], 0.f);
    }
    u32x4 o;
#pragma unroll
    for (int q = 0; q < 4; ++q) o[q] = pk2(acc[q * 2], acc[q * 2 + 1]);
    __builtin_nontemporal_store(o, reinterpret_cast<u32x4*>(Hout) +
                                       ((size_t)node * 16 + off));
}

// ------------- classifier: G[M,16] = Ah[M,128](fp16) @ Wc + bc -------------

__global__ void k_cls_h(const u32* __restrict__ Ah, const float* __restrict__ Wc,
                        const float* __restrict__ bc, float* __restrict__ G, int M) {
    __shared__ float sa[64][132];
    __shared__ float4 sw4[512];
    int tid  = threadIdx.x;
    int row0 = blockIdx.x * 64;

    for (int idx = tid; idx < 512; idx += 256)
        sw4[idx] = reinterpret_cast<const float4*>(Wc)[idx];

    const uint4* A4 = reinterpret_cast<const uint4*>(Ah);
    for (int idx = tid; idx < 64 * 16; idx += 256) {
        int r = idx >> 4, c = idx & 15;
        int gr = row0 + r;
        uint4 v = (gr < M) ? A4[(size_t)gr * 16 + c]
                           : make_uint4(0u, 0u, 0u, 0u);
        float* dst = &sa[r][c * 8];
        const u32* vv = reinterpret_cast<const u32*>(&v);
#pragma unroll
        for (int q = 0; q < 4; ++q) {
            float2 f = upk(vv[q]);
            dst[q * 2 + 0] = f.x;
            dst[q * 2 + 1] = f.y;
        }
    }
    __syncthreads();

    int tc = tid & 3;
    int tr = tid >> 2;
    float4 acc = make_float4(0.f, 0.f, 0.f, 0.f);
    for (int k4 = 0; k4 < 32; ++k4) {
        float4 a = *reinterpret_cast<const float4*>(&sa[tr][k4 * 4]);
        const float* af = reinterpret_cast<const float*>(&a);
#pragma unroll
        for (int kk = 0; kk < 4; ++kk) {
            float4 wv = sw4[(k4 * 4 + kk) * 4 + tc];
            float av = af[kk];
            acc.x += av * wv.x; acc.y += av * wv.y;
            acc.z += av * wv.z; acc.w += av * wv.w;
        }
    }
    int r = row0 + tr;
    if (r < M) {
        float4 bb = reinterpret_cast<const float4*>(bc)[tc];
        acc.x += bb.x; acc.y += bb.y; acc.z += bb.z; acc.w += bb.w;
        reinterpret_cast<float4*>(G)[(size_t)r * 4 + tc] = acc;
    }
}

// ---- final hop at width 16, fp32 ----

__global__ void k_prop16(const float* __restrict__ Gin, float* __restrict__ Out,
                         const int* __restrict__ rp, const int2* __restrict__ ew,
                         int n) {
    int g    = blockIdx.x * 64 + (threadIdx.x >> 2);
    int lane = threadIdx.x & 3;
    if (g >= n) return;
    int beg = rp[g], end = rp[g + 1];
    const float4* G4 = reinterpret_cast<const float4*>(Gin);
    float ax = 0.f, ay = 0.f, az = 0.f, aw = 0.f;
    for (int e = beg; e < end; ++e) {
        int2 p   = ew[e];
        float ww = __int_as_float(p.y);
        float4 hv = G4[(size_t)p.x * 4 + lane];
        ax += ww * hv.x; ay += ww * hv.y; az += ww * hv.z; aw += ww * hv.w;
    }
    reinterpret_cast<float4*>(Out)[(size_t)g * 4 + lane] = make_float4(ax, ay, az, aw);
}

// ---------------- host launch ----------------

extern "C" void kernel_launch(void* const* d_in, const int* in_sizes, int n_in,
                              void* d_out, int out_size, void* d_ws, size_t ws_size,
                              hipStream_t stream) {
    const float* x  = (const float*)d_in[0];
    const float* W1 = (const float*)d_in[1];
    const float* b1 = (const float*)d_in[2];
    const float* W2 = (const float*)d_in[3];
    const float* b2 = (const float*)d_in[4];
    const float* Wc = (const float*)d_in[5];
    const float* bc = (const float*)d_in[6];
    const int*   ei = (const int*)d_in[7];
    const int* srcp = ei;
    const int* dstp = ei + NEDGES;
    float* out = (float*)d_out;

    char* p = (char*)d_ws;
    auto alloc = [&](size_t bytes) -> char* {
        char* r = p;
        p += (bytes + 255) & ~(size_t)255;
        return r;
    };
    int*   deg    = (int*)  alloc(NNODES * 4);
    float* dinv   = (float*)alloc(NNODES * 4);
    int*   rp     = (int*)  alloc((NNODES + 1) * 4);
    int*   cursor = (int*)  alloc(NNODES * 4);
    int*   bsums  = (int*)  alloc(256 * 4);
    int2*  ew     = (int2*) alloc((size_t)(NEDGES + NNODES) * 8);
    float* H0     = (float*)alloc((size_t)NNODES * HID_F * 4);
    u32*   Hh0    = (u32*)  alloc((size_t)NNODES * HID_F * 2);
    u32*   Hh1    = (u32*)  alloc((size_t)NNODES * HID_F * 2);
    float* G      = (float*)alloc((size_t)NNODES * OUT_F * 4);

    const int T = 256;
    auto nb = [](int n, int t) { return (n + t - 1) / t; };

    // graph norm + CSR build
    k_init_deg<<<nb(NNODES, T), T, 0, stream>>>(deg, NNODES);
    k_count<<<nb(NEDGES, T), T, 0, stream>>>(dstp, deg, NEDGES);
    k_dinv<<<nb(NNODES, T), T, 0, stream>>>(deg, dinv, NNODES);
    int NB = nb(NNODES, 256);
    k_scan1<<<NB, 256, 0, stream>>>(deg, bsums, NNODES);
    k_scan2<<<1, 1, 0, stream>>>(bsums, NB, rp, NNODES);
    k_scan3<<<NB, 256, 0, stream>>>(deg, bsums, rp, cursor, NNODES);
    k_scatter<<<nb(NEDGES + NNODES, T), T, 0, stream>>>(srcp, dstp, dinv, cursor,
                                                        ew, NEDGES, NNODES);

    // dense part: gemm1 fp32->fp32, gemm2 fp32->fp16
    int GB = nb(NNODES, 32);
    k_gemm32<IN_F,  true,  false><<<GB, 256, 0, stream>>>(x,  W1, b1, H0,  NNODES);
    k_gemm32<HID_F, false, true ><<<GB, 256, 0, stream>>>(H0, W2, b2, Hh0, NNODES);

    // 30 hops at width 128 in fp16 (4-chunk XCD-affine), relu fused into last
    u32* cur = Hh0;
    u32* nxt = Hh1;
    int PB = nb(NNODES, 64) * 4;
    for (int i = 0; i < HOPS; ++i) {
        if (i == HOPS - 1)
            k_proph4<true ><<<PB, 256, 0, stream>>>(cur, nxt, rp, ew, NNODES);
        else
            k_proph4<false><<<PB, 256, 0, stream>>>(cur, nxt, rp, ew, NNODES);
        u32* t = cur; cur = nxt; nxt = t;
    }

    // classifier + final hop at width 16
    k_cls_h<<<nb(NNODES, 64), 256, 0, stream>>>(cur, Wc, bc, G, NNODES);
    k_prop16<<<nb(NNODES, 64), 256, 0, stream>>>(G, out, rp, ew, NNODES);
}

// Round 5
// 1220.235 us; speedup vs baseline: 2.0928x; 2.0928x over previous
//
#include <hip/hip_runtime.h>
#include <hip/hip_fp16.h>

#define NNODES 50000
#define NEDGES 800000
#define IN_F   256
#define HID_F  128
#define OUT_F  16
#define HOPS   30

typedef unsigned int u32;

union U32H2 { u32 u; __half2 h; };

__device__ inline float2 upk(u32 v) {
    U32H2 t; t.u = v;
    return __half22float2(t.h);
}
__device__ inline u32 pk2(float a, float b) {
    U32H2 t; t.h = __floats2half2_rn(a, b);
    return t.u;
}

// ---------------- graph setup kernels ----------------

__global__ void k_init_deg(int* __restrict__ deg, int n) {
    int i = blockIdx.x * blockDim.x + threadIdx.x;
    if (i < n) deg[i] = 1;  // self-loop
}

__global__ void k_count(const int* __restrict__ dst, int* __restrict__ deg, int e) {
    int i = blockIdx.x * blockDim.x + threadIdx.x;
    if (i < e) atomicAdd(&deg[dst[i]], 1);
}

__global__ void k_dinv(const int* __restrict__ deg, float* __restrict__ dinv, int n) {
    int i = blockIdx.x * blockDim.x + threadIdx.x;
    if (i < n) dinv[i] = rsqrtf((float)deg[i]);
}

__global__ void k_scan1(const int* __restrict__ deg, int* __restrict__ bsums, int n) {
    __shared__ int sh[256];
    int tid = threadIdx.x;
    int i = blockIdx.x * 256 + tid;
    sh[tid] = (i < n) ? deg[i] : 0;
    __syncthreads();
    for (int ofs = 128; ofs > 0; ofs >>= 1) {
        if (tid < ofs) sh[tid] += sh[tid + ofs];
        __syncthreads();
    }
    if (tid == 0) bsums[blockIdx.x] = sh[0];
}

__global__ void k_scan2(int* __restrict__ bsums, int nb, int* __restrict__ rp, int n) {
    if (threadIdx.x == 0 && blockIdx.x == 0) {
        int run = 0;
        for (int b = 0; b < nb; ++b) { int t = bsums[b]; bsums[b] = run; run += t; }
        rp[n] = run;
    }
}

__global__ void k_scan3(const int* __restrict__ deg, const int* __restrict__ bsums,
                        int* __restrict__ rp, int* __restrict__ cursor, int n) {
    __shared__ int sh[256];
    int tid = threadIdx.x;
    int i = blockIdx.x * 256 + tid;
    int v = (i < n) ? deg[i] : 0;
    sh[tid] = v;
    __syncthreads();
    for (int ofs = 1; ofs < 256; ofs <<= 1) {
        int t = 0;
        if (tid >= ofs) t = sh[tid - ofs];
        __syncthreads();
        sh[tid] += t;
        __syncthreads();
    }
    if (i < n) {
        int excl = sh[tid] - v + bsums[blockIdx.x];
        rp[i] = excl;
        cursor[i] = excl;
    }
}

// packed edge: .x = src node, .y = bits of edge weight
__global__ void k_scatter(const int* __restrict__ src, const int* __restrict__ dst,
                          const float* __restrict__ dinv, int* __restrict__ cursor,
                          int2* __restrict__ ew, int e, int n) {
    int t = blockIdx.x * blockDim.x + threadIdx.x;
    if (t < e) {
        int s = src[t], d = dst[t];
        int pos = atomicAdd(&cursor[d], 1);
        ew[pos] = make_int2(s, __float_as_int(dinv[s] * dinv[d]));
    } else if (t < e + n) {
        int i = t - e;
        int pos = atomicAdd(&cursor[i], 1);
        float di = dinv[i];
        ew[pos] = make_int2(i, __float_as_int(di * di));
    }
}

// sort each node's edge segment by src (ascending). Pure perf transform:
// co-resident waves then sweep src-space in sync -> gather window fits L2.
// Segments are disjoint; duplicate-src entries have identical weights, so
// output values are deterministic regardless of pre-sort order.
__global__ void k_sortseg(const int* __restrict__ rp, int2* __restrict__ ew, int n) {
    int i = blockIdx.x * blockDim.x + threadIdx.x;
    if (i >= n) return;
    int beg = rp[i], end = rp[i + 1];
    for (int a = beg + 1; a < end; ++a) {
        int2 key = ew[a];
        int b = a - 1;
        while (b >= beg && ew[b].x > key.x) { ew[b + 1] = ew[b]; --b; }
        ew[b + 1] = key;
    }
}

// ------------- GEMM: C[M,128] = (relu?)(A[M,K] @ W[K,128] + b) -------------
// 32-row x 128-col tile, 256 threads, each thread 4 rows x 4 cols.
// W fragments for step k4+1 are prefetched into registers during step k4.

template<int K, bool RELU, bool HALF_OUT>
__global__ void k_gemm32(const float* __restrict__ A, const float* __restrict__ W,
                         const float* __restrict__ b, void* __restrict__ C, int M) {
    __shared__ float sa[32][K];
    int tid  = threadIdx.x;
    int row0 = blockIdx.x * 32;
    constexpr int KV = K / 4;

    const float4* A4 = reinterpret_cast<const float4*>(A);
    for (int idx = tid; idx < 32 * KV; idx += 256) {
        int r  = idx / KV;
        int c4 = idx % KV;
        int gr = row0 + r;
        float4 v = (gr < M) ? A4[(size_t)gr * KV + c4]
                            : make_float4(0.f, 0.f, 0.f, 0.f);
        *reinterpret_cast<float4*>(&sa[r][c4 * 4]) = v;
    }
    __syncthreads();

    int tc = tid & 31;   // cols 4*tc .. 4*tc+3
    int tr = tid >> 5;   // rows 4*tr .. 4*tr+3
    float4 acc[4];
#pragma unroll
    for (int j = 0; j < 4; ++j) acc[j] = make_float4(0.f, 0.f, 0.f, 0.f);

    const float4* W4 = reinterpret_cast<const float4*>(W);
    float4 wv[4];
#pragma unroll
    for (int kk = 0; kk < 4; ++kk) wv[kk] = W4[(size_t)kk * 32 + tc];

    for (int k4 = 0; k4 < KV; ++k4) {
        float4 wn[4];
        if (k4 + 1 < KV) {
#pragma unroll
            for (int kk = 0; kk < 4; ++kk)
                wn[kk] = W4[(size_t)((k4 + 1) * 4 + kk) * 32 + tc];
        } else {
#pragma unroll
            for (int kk = 0; kk < 4; ++kk) wn[kk] = wv[kk];
        }
        float4 a[4];
#pragma unroll
        for (int j = 0; j < 4; ++j)
            a[j] = *reinterpret_cast<const float4*>(&sa[tr * 4 + j][k4 * 4]);
        const float* af = reinterpret_cast<const float*>(a);
#pragma unroll
        for (int kk = 0; kk < 4; ++kk) {
#pragma unroll
            for (int j = 0; j < 4; ++j) {
                float av = af[j * 4 + kk];
                acc[j].x += av * wv[kk].x; acc[j].y += av * wv[kk].y;
                acc[j].z += av * wv[kk].z; acc[j].w += av * wv[kk].w;
            }
        }
#pragma unroll
        for (int kk = 0; kk < 4; ++kk) wv[kk] = wn[kk];
    }

    float4 bb = reinterpret_cast<const float4*>(b)[tc];
#pragma unroll
    for (int j = 0; j < 4; ++j) {
        int r = row0 + tr * 4 + j;
        if (r < M) {
            float4 v;
            v.x = acc[j].x + bb.x; v.y = acc[j].y + bb.y;
            v.z = acc[j].z + bb.z; v.w = acc[j].w + bb.w;
            if (RELU) {
                v.x = fmaxf(v.x, 0.f); v.y = fmaxf(v.y, 0.f);
                v.z = fmaxf(v.z, 0.f); v.w = fmaxf(v.w, 0.f);
            }
            if (HALF_OUT) {
                u32 lo = pk2(v.x, v.y), hi = pk2(v.z, v.w);
                reinterpret_cast<uint2*>(C)[(size_t)r * 32 + tc] = make_uint2(lo, hi);
            } else {
                reinterpret_cast<float4*>(C)[(size_t)r * 32 + tc] = v;
            }
        }
    }
}

// ---- propagation at width 128, H in fp16, accumulate fp32 ----
// 8 lanes per node, 16 features per lane (2x uint4 = 16 halves).

template<bool RELU>
__global__ void k_proph(const u32* __restrict__ Hin, u32* __restrict__ Hout,
                        const int* __restrict__ rp, const int2* __restrict__ ew,
                        int n) {
    int grp  = threadIdx.x >> 3;   // 32 nodes per block
    int lane = threadIdx.x & 7;
    int node = blockIdx.x * 32 + grp;
    if (node >= n) return;
    int beg = rp[node], end = rp[node + 1];
    const uint4* H4 = reinterpret_cast<const uint4*>(Hin);  // row = 16 uint4

    float acc[16];
#pragma unroll
    for (int i = 0; i < 16; ++i) acc[i] = 0.f;

    auto body = [&](int e) {
        int2 p   = ew[e];
        float ww = __int_as_float(p.y);
        size_t base = (size_t)p.x * 16 + lane * 2;
        uint4 v0 = H4[base];
        uint4 v1 = H4[base + 1];
        const u32* vv = reinterpret_cast<const u32*>(&v0);
#pragma unroll
        for (int q = 0; q < 4; ++q) {
            float2 f = upk(vv[q]);
            acc[q * 2 + 0] += ww * f.x;
            acc[q * 2 + 1] += ww * f.y;
        }
        const u32* vw = reinterpret_cast<const u32*>(&v1);
#pragma unroll
        for (int q = 0; q < 4; ++q) {
            float2 f = upk(vw[q]);
            acc[8 + q * 2 + 0] += ww * f.x;
            acc[8 + q * 2 + 1] += ww * f.y;
        }
    };

    int e = beg;
    for (; e + 1 < end; e += 2) { body(e); body(e + 1); }
    if (e < end) body(e);

    if (RELU) {
#pragma unroll
        for (int i = 0; i < 16; ++i) acc[i] = fmaxf(acc[i], 0.f);
    }
    uint4 o0, o1;
    u32* ov = reinterpret_cast<u32*>(&o0);
#pragma unroll
    for (int q = 0; q < 4; ++q) ov[q] = pk2(acc[q * 2], acc[q * 2 + 1]);
    u32* ow = reinterpret_cast<u32*>(&o1);
#pragma unroll
    for (int q = 0; q < 4; ++q) ow[q] = pk2(acc[8 + q * 2], acc[8 + q * 2 + 1]);
    size_t obase = (size_t)node * 16 + lane * 2;
    reinterpret_cast<uint4*>(Hout)[obase]     = o0;
    reinterpret_cast<uint4*>(Hout)[obase + 1] = o1;
}

// ------------- classifier: G[M,16] = Ah[M,128](fp16) @ Wc + bc -------------

__global__ void k_cls_h(const u32* __restrict__ Ah, const float* __restrict__ Wc,
                        const float* __restrict__ bc, float* __restrict__ G, int M) {
    __shared__ float sa[64][132];
    __shared__ float4 sw4[512];
    int tid  = threadIdx.x;
    int row0 = blockIdx.x * 64;

    for (int idx = tid; idx < 512; idx += 256)
        sw4[idx] = reinterpret_cast<const float4*>(Wc)[idx];

    const uint4* A4 = reinterpret_cast<const uint4*>(Ah);
    for (int idx = tid; idx < 64 * 16; idx += 256) {
        int r = idx >> 4, c = idx & 15;
        int gr = row0 + r;
        uint4 v = (gr < M) ? A4[(size_t)gr * 16 + c]
                           : make_uint4(0u, 0u, 0u, 0u);
        float* dst = &sa[r][c * 8];
        const u32* vv = reinterpret_cast<const u32*>(&v);
#pragma unroll
        for (int q = 0; q < 4; ++q) {
            float2 f = upk(vv[q]);
            dst[q * 2 + 0] = f.x;
            dst[q * 2 + 1] = f.y;
        }
    }
    __syncthreads();

    int tc = tid & 3;
    int tr = tid >> 2;
    float4 acc = make_float4(0.f, 0.f, 0.f, 0.f);
    for (int k4 = 0; k4 < 32; ++k4) {
        float4 a = *reinterpret_cast<const float4*>(&sa[tr][k4 * 4]);
        const float* af = reinterpret_cast<const float*>(&a);
#pragma unroll
        for (int kk = 0; kk < 4; ++kk) {
            float4 wv = sw4[(k4 * 4 + kk) * 4 + tc];
            float av = af[kk];
            acc.x += av * wv.x; acc.y += av * wv.y;
            acc.z += av * wv.z; acc.w += av * wv.w;
        }
    }
    int r = row0 + tr;
    if (r < M) {
        float4 bb = reinterpret_cast<const float4*>(bc)[tc];
        acc.x += bb.x; acc.y += bb.y; acc.z += bb.z; acc.w += bb.w;
        reinterpret_cast<float4*>(G)[(size_t)r * 4 + tc] = acc;
    }
}

// ---- final hop at width 16, fp32 ----

__global__ void k_prop16(const float* __restrict__ Gin, float* __restrict__ Out,
                         const int* __restrict__ rp, const int2* __restrict__ ew,
                         int n) {
    int g    = blockIdx.x * 64 + (threadIdx.x >> 2);
    int lane = threadIdx.x & 3;
    if (g >= n) return;
    int beg = rp[g], end = rp[g + 1];
    const float4* G4 = reinterpret_cast<const float4*>(Gin);
    float ax = 0.f, ay = 0.f, az = 0.f, aw = 0.f;
    for (int e = beg; e < end; ++e) {
        int2 p   = ew[e];
        float ww = __int_as_float(p.y);
        float4 hv = G4[(size_t)p.x * 4 + lane];
        ax += ww * hv.x; ay += ww * hv.y; az += ww * hv.z; aw += ww * hv.w;
    }
    reinterpret_cast<float4*>(Out)[(size_t)g * 4 + lane] = make_float4(ax, ay, az, aw);
}

// ---------------- host launch ----------------

extern "C" void kernel_launch(void* const* d_in, const int* in_sizes, int n_in,
                              void* d_out, int out_size, void* d_ws, size_t ws_size,
                              hipStream_t stream) {
    const float* x  = (const float*)d_in[0];
    const float* W1 = (const float*)d_in[1];
    const float* b1 = (const float*)d_in[2];
    const float* W2 = (const float*)d_in[3];
    const float* b2 = (const float*)d_in[4];
    const float* Wc = (const float*)d_in[5];
    const float* bc = (const float*)d_in[6];
    const int*   ei = (const int*)d_in[7];
    const int* srcp = ei;
    const int* dstp = ei + NEDGES;
    float* out = (float*)d_out;

    char* p = (char*)d_ws;
    auto alloc = [&](size_t bytes) -> char* {
        char* r = p;
        p += (bytes + 255) & ~(size_t)255;
        return r;
    };
    int*   deg    = (int*)  alloc(NNODES * 4);
    float* dinv   = (float*)alloc(NNODES * 4);
    int*   rp     = (int*)  alloc((NNODES + 1) * 4);
    int*   cursor = (int*)  alloc(NNODES * 4);
    int*   bsums  = (int*)  alloc(256 * 4);
    int2*  ew     = (int2*) alloc((size_t)(NEDGES + NNODES) * 8);
    float* H0     = (float*)alloc((size_t)NNODES * HID_F * 4);
    u32*   Hh0    = (u32*)  alloc((size_t)NNODES * HID_F * 2);
    u32*   Hh1    = (u32*)  alloc((size_t)NNODES * HID_F * 2);
    float* G      = (float*)alloc((size_t)NNODES * OUT_F * 4);

    const int T = 256;
    auto nb = [](int n, int t) { return (n + t - 1) / t; };

    // graph norm + CSR build (+ per-node src-sort)
    k_init_deg<<<nb(NNODES, T), T, 0, stream>>>(deg, NNODES);
    k_count<<<nb(NEDGES, T), T, 0, stream>>>(dstp, deg, NEDGES);
    k_dinv<<<nb(NNODES, T), T, 0, stream>>>(deg, dinv, NNODES);
    int NB = nb(NNODES, 256);
    k_scan1<<<NB, 256, 0, stream>>>(deg, bsums, NNODES);
    k_scan2<<<1, 1, 0, stream>>>(bsums, NB, rp, NNODES);
    k_scan3<<<NB, 256, 0, stream>>>(deg, bsums, rp, cursor, NNODES);
    k_scatter<<<nb(NEDGES + NNODES, T), T, 0, stream>>>(srcp, dstp, dinv, cursor,
                                                        ew, NEDGES, NNODES);
    k_sortseg<<<nb(NNODES, T), T, 0, stream>>>(rp, ew, NNODES);

    // dense part: gemm1 fp32->fp32, gemm2 fp32->fp16
    int GB = nb(NNODES, 32);
    k_gemm32<IN_F,  true,  false><<<GB, 256, 0, stream>>>(x,  W1, b1, H0,  NNODES);
    k_gemm32<HID_F, false, true ><<<GB, 256, 0, stream>>>(H0, W2, b2, Hh0, NNODES);

    // 30 hops at width 128 in fp16, relu fused into last hop
    u32* cur = Hh0;
    u32* nxt = Hh1;
    int PB = nb(NNODES, 32);
    for (int i = 0; i < HOPS; ++i) {
        if (i == HOPS - 1)
            k_proph<true ><<<PB, 256, 0, stream>>>(cur, nxt, rp, ew, NNODES);
        else
            k_proph<false><<<PB, 256, 0, stream>>>(cur, nxt, rp, ew, NNODES);
        u32* t = cur; cur = nxt; nxt = t;
    }

    // classifier + final hop at width 16
    k_cls_h<<<nb(NNODES, 64), 256, 0, stream>>>(cur, Wc, bc, G, NNODES);
    k_prop16<<<nb(NNODES, 64), 256, 0, stream>>>(G, out, rp, ew, NNODES);
}

// Round 6
// 1144.376 us; speedup vs baseline: 2.2316x; 1.0663x over previous
//
#include <hip/hip_runtime.h>
#include <hip/hip_fp16.h>

#define NNODES 50000
#define NEDGES 800000
#define IN_F   256
#define HID_F  128
#define OUT_F  16
#define HOPS   30

typedef unsigned int u32;

union U32H2 { u32 u; __half2 h; };

__device__ inline float2 upk(u32 v) {
    U32H2 t; t.u = v;
    return __half22float2(t.h);
}
__device__ inline u32 pk2(float a, float b) {
    U32H2 t; t.h = __floats2half2_rn(a, b);
    return t.u;
}

// ---------------- graph setup kernels ----------------

__global__ void k_init_deg(int* __restrict__ deg, int n) {
    int i = blockIdx.x * blockDim.x + threadIdx.x;
    if (i < n) deg[i] = 1;  // self-loop
}

__global__ void k_count(const int* __restrict__ dst, int* __restrict__ deg, int e) {
    int i = blockIdx.x * blockDim.x + threadIdx.x;
    if (i < e) atomicAdd(&deg[dst[i]], 1);
}

__global__ void k_dinv(const int* __restrict__ deg, float* __restrict__ dinv, int n) {
    int i = blockIdx.x * blockDim.x + threadIdx.x;
    if (i < n) dinv[i] = rsqrtf((float)deg[i]);
}

__global__ void k_scan1(const int* __restrict__ deg, int* __restrict__ bsums, int n) {
    __shared__ int sh[256];
    int tid = threadIdx.x;
    int i = blockIdx.x * 256 + tid;
    sh[tid] = (i < n) ? deg[i] : 0;
    __syncthreads();
    for (int ofs = 128; ofs > 0; ofs >>= 1) {
        if (tid < ofs) sh[tid] += sh[tid + ofs];
        __syncthreads();
    }
    if (tid == 0) bsums[blockIdx.x] = sh[0];
}

__global__ void k_scan2(int* __restrict__ bsums, int nb, int* __restrict__ rp, int n) {
    if (threadIdx.x == 0 && blockIdx.x == 0) {
        int run = 0;
        for (int b = 0; b < nb; ++b) { int t = bsums[b]; bsums[b] = run; run += t; }
        rp[n] = run;
    }
}

__global__ void k_scan3(const int* __restrict__ deg, const int* __restrict__ bsums,
                        int* __restrict__ rp, int* __restrict__ cursor, int n) {
    __shared__ int sh[256];
    int tid = threadIdx.x;
    int i = blockIdx.x * 256 + tid;
    int v = (i < n) ? deg[i] : 0;
    sh[tid] = v;
    __syncthreads();
    for (int ofs = 1; ofs < 256; ofs <<= 1) {
        int t = 0;
        if (tid >= ofs) t = sh[tid - ofs];
        __syncthreads();
        sh[tid] += t;
        __syncthreads();
    }
    if (i < n) {
        int excl = sh[tid] - v + bsums[blockIdx.x];
        rp[i] = excl;
        cursor[i] = excl;
    }
}

// packed edge: .x = src node, .y = bits of edge weight
__global__ void k_scatter(const int* __restrict__ src, const int* __restrict__ dst,
                          const float* __restrict__ dinv, int* __restrict__ cursor,
                          int2* __restrict__ ew, int e, int n) {
    int t = blockIdx.x * blockDim.x + threadIdx.x;
    if (t < e) {
        int s = src[t], d = dst[t];
        int pos = atomicAdd(&cursor[d], 1);
        ew[pos] = make_int2(s, __float_as_int(dinv[s] * dinv[d]));
    } else if (t < e + n) {
        int i = t - e;
        int pos = atomicAdd(&cursor[i], 1);
        float di = dinv[i];
        ew[pos] = make_int2(i, __float_as_int(di * di));
    }
}

// wave-parallel in-place segment sort by src: one 64-lane wave per node.
// Lane l owns slot beg+l; rank = #{k: s_k < s_l or (s_k==s_l and k<l)} via
// 64 uniform shuffles; whole segment lives in this wave's registers, so
// in-place rescatter is race-free. deg>64 is ~impossible (Poisson 17);
// fallback leaves segment unsorted (sort is perf-only).
__global__ void k_sortwave(const int* __restrict__ rp, int2* __restrict__ ew, int n) {
    int node = blockIdx.x * 4 + (threadIdx.x >> 6);
    int lane = threadIdx.x & 63;
    if (node >= n) return;
    int beg = rp[node], end = rp[node + 1];
    int deg = end - beg;
    if (deg > 64) return;  // leave unsorted (perf-only transform)
    int2 my = make_int2(0x7fffffff, 0);
    if (lane < deg) my = ew[beg + lane];
    int rank = 0;
#pragma unroll 8
    for (int k = 0; k < 64; ++k) {
        int sk = __shfl(my.x, k);
        rank += (sk < my.x) || (sk == my.x && k < lane);
    }
    if (lane < deg) ew[beg + rank] = my;
}

// ------------- GEMM: C[M,128] = (relu?)(A[M,K] @ W[K,128] + b) -------------
// 32-row x 128-col tile, 256 threads, each thread 4 rows x 4 cols.
// W fragments for step k4+1 are prefetched into registers during step k4.

template<int K, bool RELU, bool HALF_OUT>
__global__ void k_gemm32(const float* __restrict__ A, const float* __restrict__ W,
                         const float* __restrict__ b, void* __restrict__ C, int M) {
    __shared__ float sa[32][K];
    int tid  = threadIdx.x;
    int row0 = blockIdx.x * 32;
    constexpr int KV = K / 4;

    const float4* A4 = reinterpret_cast<const float4*>(A);
    for (int idx = tid; idx < 32 * KV; idx += 256) {
        int r  = idx / KV;
        int c4 = idx % KV;
        int gr = row0 + r;
        float4 v = (gr < M) ? A4[(size_t)gr * KV + c4]
                            : make_float4(0.f, 0.f, 0.f, 0.f);
        *reinterpret_cast<float4*>(&sa[r][c4 * 4]) = v;
    }
    __syncthreads();

    int tc = tid & 31;   // cols 4*tc .. 4*tc+3
    int tr = tid >> 5;   // rows 4*tr .. 4*tr+3
    float4 acc[4];
#pragma unroll
    for (int j = 0; j < 4; ++j) acc[j] = make_float4(0.f, 0.f, 0.f, 0.f);

    const float4* W4 = reinterpret_cast<const float4*>(W);
    float4 wv[4];
#pragma unroll
    for (int kk = 0; kk < 4; ++kk) wv[kk] = W4[(size_t)kk * 32 + tc];

    for (int k4 = 0; k4 < KV; ++k4) {
        float4 wn[4];
        if (k4 + 1 < KV) {
#pragma unroll
            for (int kk = 0; kk < 4; ++kk)
                wn[kk] = W4[(size_t)((k4 + 1) * 4 + kk) * 32 + tc];
        } else {
#pragma unroll
            for (int kk = 0; kk < 4; ++kk) wn[kk] = wv[kk];
        }
        float4 a[4];
#pragma unroll
        for (int j = 0; j < 4; ++j)
            a[j] = *reinterpret_cast<const float4*>(&sa[tr * 4 + j][k4 * 4]);
        const float* af = reinterpret_cast<const float*>(a);
#pragma unroll
        for (int kk = 0; kk < 4; ++kk) {
#pragma unroll
            for (int j = 0; j < 4; ++j) {
                float av = af[j * 4 + kk];
                acc[j].x += av * wv[kk].x; acc[j].y += av * wv[kk].y;
                acc[j].z += av * wv[kk].z; acc[j].w += av * wv[kk].w;
            }
        }
#pragma unroll
        for (int kk = 0; kk < 4; ++kk) wv[kk] = wn[kk];
    }

    float4 bb = reinterpret_cast<const float4*>(b)[tc];
#pragma unroll
    for (int j = 0; j < 4; ++j) {
        int r = row0 + tr * 4 + j;
        if (r < M) {
            float4 v;
            v.x = acc[j].x + bb.x; v.y = acc[j].y + bb.y;
            v.z = acc[j].z + bb.z; v.w = acc[j].w + bb.w;
            if (RELU) {
                v.x = fmaxf(v.x, 0.f); v.y = fmaxf(v.y, 0.f);
                v.z = fmaxf(v.z, 0.f); v.w = fmaxf(v.w, 0.f);
            }
            if (HALF_OUT) {
                u32 lo = pk2(v.x, v.y), hi = pk2(v.z, v.w);
                reinterpret_cast<uint2*>(C)[(size_t)r * 32 + tc] = make_uint2(lo, hi);
            } else {
                reinterpret_cast<float4*>(C)[(size_t)r * 32 + tc] = v;
            }
        }
    }
}

// ---- propagation at width 128, H in fp16, accumulate fp32 ----
// 16 lanes per node, one uint4 (8 halves) per lane: 1 gather per edge per
// lane (short serial chain), x2 unroll for MLP.

template<bool RELU>
__global__ void k_proph(const u32* __restrict__ Hin, u32* __restrict__ Hout,
                        const int* __restrict__ rp, const int2* __restrict__ ew,
                        int n) {
    int grp  = threadIdx.x >> 4;   // 16 nodes per block
    int lane = threadIdx.x & 15;
    int node = blockIdx.x * 16 + grp;
    if (node >= n) return;
    int beg = rp[node], end = rp[node + 1];
    const uint4* H4 = reinterpret_cast<const uint4*>(Hin);  // row = 16 uint4

    float acc[8];
#pragma unroll
    for (int i = 0; i < 8; ++i) acc[i] = 0.f;

    auto body = [&](int e) {
        int2 p   = ew[e];
        float ww = __int_as_float(p.y);
        uint4 v  = H4[(size_t)p.x * 16 + lane];
        const u32* vv = reinterpret_cast<const u32*>(&v);
#pragma unroll
        for (int q = 0; q < 4; ++q) {
            float2 f = upk(vv[q]);
            acc[q * 2 + 0] += ww * f.x;
            acc[q * 2 + 1] += ww * f.y;
        }
    };

    int e = beg;
    for (; e + 1 < end; e += 2) { body(e); body(e + 1); }
    if (e < end) body(e);

    if (RELU) {
#pragma unroll
        for (int i = 0; i < 8; ++i) acc[i] = fmaxf(acc[i], 0.f);
    }
    uint4 o;
    u32* ov = reinterpret_cast<u32*>(&o);
#pragma unroll
    for (int q = 0; q < 4; ++q) ov[q] = pk2(acc[q * 2], acc[q * 2 + 1]);
    reinterpret_cast<uint4*>(Hout)[(size_t)node * 16 + lane] = o;
}

// ------------- classifier: G[M,16] = Ah[M,128](fp16) @ Wc + bc -------------

__global__ void k_cls_h(const u32* __restrict__ Ah, const float* __restrict__ Wc,
                        const float* __restrict__ bc, float* __restrict__ G, int M) {
    __shared__ float sa[64][132];
    __shared__ float4 sw4[512];
    int tid  = threadIdx.x;
    int row0 = blockIdx.x * 64;

    for (int idx = tid; idx < 512; idx += 256)
        sw4[idx] = reinterpret_cast<const float4*>(Wc)[idx];

    const uint4* A4 = reinterpret_cast<const uint4*>(Ah);
    for (int idx = tid; idx < 64 * 16; idx += 256) {
        int r = idx >> 4, c = idx & 15;
        int gr = row0 + r;
        uint4 v = (gr < M) ? A4[(size_t)gr * 16 + c]
                           : make_uint4(0u, 0u, 0u, 0u);
        float* dst = &sa[r][c * 8];
        const u32* vv = reinterpret_cast<const u32*>(&v);
#pragma unroll
        for (int q = 0; q < 4; ++q) {
            float2 f = upk(vv[q]);
            dst[q * 2 + 0] = f.x;
            dst[q * 2 + 1] = f.y;
        }
    }
    __syncthreads();

    int tc = tid & 3;
    int tr = tid >> 2;
    float4 acc = make_float4(0.f, 0.f, 0.f, 0.f);
    for (int k4 = 0; k4 < 32; ++k4) {
        float4 a = *reinterpret_cast<const float4*>(&sa[tr][k4 * 4]);
        const float* af = reinterpret_cast<const float*>(&a);
#pragma unroll
        for (int kk = 0; kk < 4; ++kk) {
            float4 wv = sw4[(k4 * 4 + kk) * 4 + tc];
            float av = af[kk];
            acc.x += av * wv.x; acc.y += av * wv.y;
            acc.z += av * wv.z; acc.w += av * wv.w;
        }
    }
    int r = row0 + tr;
    if (r < M) {
        float4 bb = reinterpret_cast<const float4*>(bc)[tc];
        acc.x += bb.x; acc.y += bb.y; acc.z += bb.z; acc.w += bb.w;
        reinterpret_cast<float4*>(G)[(size_t)r * 4 + tc] = acc;
    }
}

// ---- final hop at width 16, fp32 ----

__global__ void k_prop16(const float* __restrict__ Gin, float* __restrict__ Out,
                         const int* __restrict__ rp, const int2* __restrict__ ew,
                         int n) {
    int g    = blockIdx.x * 64 + (threadIdx.x >> 2);
    int lane = threadIdx.x & 3;
    if (g >= n) return;
    int beg = rp[g], end = rp[g + 1];
    const float4* G4 = reinterpret_cast<const float4*>(Gin);
    float ax = 0.f, ay = 0.f, az = 0.f, aw = 0.f;
    for (int e = beg; e < end; ++e) {
        int2 p   = ew[e];
        float ww = __int_as_float(p.y);
        float4 hv = G4[(size_t)p.x * 4 + lane];
        ax += ww * hv.x; ay += ww * hv.y; az += ww * hv.z; aw += ww * hv.w;
    }
    reinterpret_cast<float4*>(Out)[(size_t)g * 4 + lane] = make_float4(ax, ay, az, aw);
}

// ---------------- host launch ----------------

extern "C" void kernel_launch(void* const* d_in, const int* in_sizes, int n_in,
                              void* d_out, int out_size, void* d_ws, size_t ws_size,
                              hipStream_t stream) {
    const float* x  = (const float*)d_in[0];
    const float* W1 = (const float*)d_in[1];
    const float* b1 = (const float*)d_in[2];
    const float* W2 = (const float*)d_in[3];
    const float* b2 = (const float*)d_in[4];
    const float* Wc = (const float*)d_in[5];
    const float* bc = (const float*)d_in[6];
    const int*   ei = (const int*)d_in[7];
    const int* srcp = ei;
    const int* dstp = ei + NEDGES;
    float* out = (float*)d_out;

    char* p = (char*)d_ws;
    auto alloc = [&](size_t bytes) -> char* {
        char* r = p;
        p += (bytes + 255) & ~(size_t)255;
        return r;
    };
    int*   deg    = (int*)  alloc(NNODES * 4);
    float* dinv   = (float*)alloc(NNODES * 4);
    int*   rp     = (int*)  alloc((NNODES + 1) * 4);
    int*   cursor = (int*)  alloc(NNODES * 4);
    int*   bsums  = (int*)  alloc(256 * 4);
    int2*  ew     = (int2*) alloc((size_t)(NEDGES + NNODES) * 8);
    float* H0     = (float*)alloc((size_t)NNODES * HID_F * 4);
    u32*   Hh0    = (u32*)  alloc((size_t)NNODES * HID_F * 2);
    u32*   Hh1    = (u32*)  alloc((size_t)NNODES * HID_F * 2);
    float* G      = (float*)alloc((size_t)NNODES * OUT_F * 4);

    const int T = 256;
    auto nb = [](int n, int t) { return (n + t - 1) / t; };

    // graph norm + CSR build (+ per-node wave sort)
    k_init_deg<<<nb(NNODES, T), T, 0, stream>>>(deg, NNODES);
    k_count<<<nb(NEDGES, T), T, 0, stream>>>(dstp, deg, NEDGES);
    k_dinv<<<nb(NNODES, T), T, 0, stream>>>(deg, dinv, NNODES);
    int NB = nb(NNODES, 256);
    k_scan1<<<NB, 256, 0, stream>>>(deg, bsums, NNODES);
    k_scan2<<<1, 1, 0, stream>>>(bsums, NB, rp, NNODES);
    k_scan3<<<NB, 256, 0, stream>>>(deg, bsums, rp, cursor, NNODES);
    k_scatter<<<nb(NEDGES + NNODES, T), T, 0, stream>>>(srcp, dstp, dinv, cursor,
                                                        ew, NEDGES, NNODES);
    k_sortwave<<<nb(NNODES, 4), 256, 0, stream>>>(rp, ew, NNODES);

    // dense part: gemm1 fp32->fp32, gemm2 fp32->fp16
    int GB = nb(NNODES, 32);
    k_gemm32<IN_F,  true,  false><<<GB, 256, 0, stream>>>(x,  W1, b1, H0,  NNODES);
    k_gemm32<HID_F, false, true ><<<GB, 256, 0, stream>>>(H0, W2, b2, Hh0, NNODES);

    // 30 hops at width 128 in fp16, relu fused into last hop
    u32* cur = Hh0;
    u32* nxt = Hh1;
    int PB = nb(NNODES, 16);
    for (int i = 0; i < HOPS; ++i) {
        if (i == HOPS - 1)
            k_proph<true ><<<PB, 256, 0, stream>>>(cur, nxt, rp, ew, NNODES);
        else
            k_proph<false><<<PB, 256, 0, stream>>>(cur, nxt, rp, ew, NNODES);
        u32* t = cur; cur = nxt; nxt = t;
    }

    // classifier + final hop at width 16
    k_cls_h<<<nb(NNODES, 64), 256, 0, stream>>>(cur, Wc, bc, G, NNODES);
    k_prop16<<<nb(NNODES, 64), 256, 0, stream>>>(G, out, rp, ew, NNODES);
}

// Round 7
// 1121.584 us; speedup vs baseline: 2.2769x; 1.0203x over previous
//
#include <hip/hip_runtime.h>
#include <hip/hip_fp16.h>

#define NNODES 50000
#define NEDGES 800000
#define IN_F   256
#define HID_F  128
#define OUT_F  16
#define HOPS   30
#define MPAD   50048   // NNODES rounded up to 64-row GEMM tiles

typedef unsigned int u32;
typedef _Float16 f16;
typedef f16 f16x8 __attribute__((ext_vector_type(8)));
typedef float f32x4 __attribute__((ext_vector_type(4)));

union U32H2 { u32 u; __half2 h; };

__device__ inline float2 upk(u32 v) {
    U32H2 t; t.u = v;
    return __half22float2(t.h);
}
__device__ inline u32 pk2(float a, float b) {
    U32H2 t; t.h = __floats2half2_rn(a, b);
    return t.u;
}

// ---------------- graph setup kernels ----------------

__global__ void k_init_deg(int* __restrict__ deg, int n) {
    int i = blockIdx.x * blockDim.x + threadIdx.x;
    if (i < n) deg[i] = 1;  // self-loop
}

__global__ void k_count(const int* __restrict__ dst, int* __restrict__ deg, int e) {
    int i = blockIdx.x * blockDim.x + threadIdx.x;
    if (i < e) atomicAdd(&deg[dst[i]], 1);
}

__global__ void k_dinv(const int* __restrict__ deg, float* __restrict__ dinv, int n) {
    int i = blockIdx.x * blockDim.x + threadIdx.x;
    if (i < n) dinv[i] = rsqrtf((float)deg[i]);
}

__global__ void k_scan1(const int* __restrict__ deg, int* __restrict__ bsums, int n) {
    __shared__ int sh[256];
    int tid = threadIdx.x;
    int i = blockIdx.x * 256 + tid;
    sh[tid] = (i < n) ? deg[i] : 0;
    __syncthreads();
    for (int ofs = 128; ofs > 0; ofs >>= 1) {
        if (tid < ofs) sh[tid] += sh[tid + ofs];
        __syncthreads();
    }
    if (tid == 0) bsums[blockIdx.x] = sh[0];
}

__global__ void k_scan2(int* __restrict__ bsums, int nb, int* __restrict__ rp, int n) {
    if (threadIdx.x == 0 && blockIdx.x == 0) {
        int run = 0;
        for (int b = 0; b < nb; ++b) { int t = bsums[b]; bsums[b] = run; run += t; }
        rp[n] = run;
    }
}

__global__ void k_scan3(const int* __restrict__ deg, const int* __restrict__ bsums,
                        int* __restrict__ rp, int* __restrict__ cursor, int n) {
    __shared__ int sh[256];
    int tid = threadIdx.x;
    int i = blockIdx.x * 256 + tid;
    int v = (i < n) ? deg[i] : 0;
    sh[tid] = v;
    __syncthreads();
    for (int ofs = 1; ofs < 256; ofs <<= 1) {
        int t = 0;
        if (tid >= ofs) t = sh[tid - ofs];
        __syncthreads();
        sh[tid] += t;
        __syncthreads();
    }
    if (i < n) {
        int excl = sh[tid] - v + bsums[blockIdx.x];
        rp[i] = excl;
        cursor[i] = excl;
    }
}

// packed edge: .x = src node, .y = bits of edge weight
__global__ void k_scatter(const int* __restrict__ src, const int* __restrict__ dst,
                          const float* __restrict__ dinv, int* __restrict__ cursor,
                          int2* __restrict__ ew, int e, int n) {
    int t = blockIdx.x * blockDim.x + threadIdx.x;
    if (t < e) {
        int s = src[t], d = dst[t];
        int pos = atomicAdd(&cursor[d], 1);
        ew[pos] = make_int2(s, __float_as_int(dinv[s] * dinv[d]));
    } else if (t < e + n) {
        int i = t - e;
        int pos = atomicAdd(&cursor[i], 1);
        float di = dinv[i];
        ew[pos] = make_int2(i, __float_as_int(di * di));
    }
}

// wave-parallel in-place segment sort by src (one 64-lane wave per node).
__global__ void k_sortwave(const int* __restrict__ rp, int2* __restrict__ ew, int n) {
    int node = blockIdx.x * 4 + (threadIdx.x >> 6);
    int lane = threadIdx.x & 63;
    if (node >= n) return;
    int beg = rp[node], end = rp[node + 1];
    int deg = end - beg;
    if (deg > 64) return;  // leave unsorted (perf-only transform)
    int2 my = make_int2(0x7fffffff, 0);
    if (lane < deg) my = ew[beg + lane];
    int rank = 0;
#pragma unroll 8
    for (int k = 0; k < 64; ++k) {
        int sk = __shfl(my.x, k);
        rank += (sk < my.x) || (sk == my.x && k < lane);
    }
    if (lane < deg) ew[beg + rank] = my;
}

// ---------------- fp16 casts ----------------

__global__ void k_cast_x(const float* __restrict__ in, f16* __restrict__ out, int n) {
    int i = blockIdx.x * blockDim.x + threadIdx.x;
    int stride = gridDim.x * blockDim.x;
    for (; i < n / 4; i += stride) {
        float4 v = reinterpret_cast<const float4*>(in)[i];
        f16 o[4] = {(f16)v.x, (f16)v.y, (f16)v.z, (f16)v.w};
        *reinterpret_cast<uint2*>(&reinterpret_cast<f16*>(out)[i * 4]) =
            *reinterpret_cast<uint2*>(o);
    }
}

// W[K][NC] fp32 -> Wt[NC][K] fp16
template<int K, int NC>
__global__ void k_cast_wt(const float* __restrict__ W, f16* __restrict__ Wt) {
    int i = blockIdx.x * blockDim.x + threadIdx.x;
    if (i < K * NC) {
        int k = i / NC, c = i % NC;
        Wt[(size_t)c * K + k] = (f16)W[i];
    }
}

// ------- MFMA GEMM: C[M,128](fp16) = (relu?)(A[M,K](f16) @ Wt^T + b) -------
// 64-row tile, 4 waves x 16 rows, N_rep=8 (128 cols), K-step 32.
// A rows padded to MPAD (pad rows read garbage, results discarded by guard).
// Operand layout: lane&15 -> row(A)/col(B), 8 consecutive k per lane-group;
// identical k-mapping for A and B makes the result invariant to the HW's
// within-chunk k order. C/D: col=lane&15, row=4*(lane>>4)+reg (m89-verified).

template<int K, bool RELU>
__global__ __launch_bounds__(256)
void k_gemm_mfma(const f16* __restrict__ A, const f16* __restrict__ Wt,
                 const float* __restrict__ b, f16* __restrict__ C, int M) {
    int wid  = threadIdx.x >> 6;
    int lane = threadIdx.x & 63;
    int rowW = blockIdx.x * 64 + wid * 16;   // this wave's 16 rows
    int rl   = lane & 15;
    int kc   = (lane >> 4) * 8;

    f32x4 acc[8];
#pragma unroll
    for (int n = 0; n < 8; ++n) acc[n] = (f32x4)0.f;

    const f16* Arow = A + (size_t)(rowW + rl) * K;
#pragma unroll
    for (int k0 = 0; k0 < K; k0 += 32) {
        f16x8 aF = *reinterpret_cast<const f16x8*>(Arow + k0 + kc);
#pragma unroll
        for (int n = 0; n < 8; ++n) {
            f16x8 bF = *reinterpret_cast<const f16x8*>(
                Wt + (size_t)(n * 16 + rl) * K + k0 + kc);
            acc[n] = __builtin_amdgcn_mfma_f32_16x16x32_f16(aF, bF, acc[n], 0, 0, 0);
        }
    }

#pragma unroll
    for (int n = 0; n < 8; ++n) {
        int col = n * 16 + rl;
        float bias = b[col];
#pragma unroll
        for (int j = 0; j < 4; ++j) {
            int row = rowW + 4 * (lane >> 4) + j;
            if (row < M) {
                float s = acc[n][j] + bias;
                if (RELU) s = fmaxf(s, 0.f);
                C[(size_t)row * 128 + col] = (f16)s;
            }
        }
    }
}

// ---- propagation at width 128, H in fp16, accumulate fp32 ----
// 16 lanes per node, one uint4 (8 halves) per lane.

template<bool RELU>
__global__ void k_proph(const u32* __restrict__ Hin, u32* __restrict__ Hout,
                        const int* __restrict__ rp, const int2* __restrict__ ew,
                        int n) {
    int grp  = threadIdx.x >> 4;   // 16 nodes per block
    int lane = threadIdx.x & 15;
    int node = blockIdx.x * 16 + grp;
    if (node >= n) return;
    int beg = rp[node], end = rp[node + 1];
    const uint4* H4 = reinterpret_cast<const uint4*>(Hin);  // row = 16 uint4

    float acc[8];
#pragma unroll
    for (int i = 0; i < 8; ++i) acc[i] = 0.f;

    auto body = [&](int e) {
        int2 p   = ew[e];
        float ww = __int_as_float(p.y);
        uint4 v  = H4[(size_t)p.x * 16 + lane];
        const u32* vv = reinterpret_cast<const u32*>(&v);
#pragma unroll
        for (int q = 0; q < 4; ++q) {
            float2 f = upk(vv[q]);
            acc[q * 2 + 0] += ww * f.x;
            acc[q * 2 + 1] += ww * f.y;
        }
    };

    int e = beg;
    for (; e + 1 < end; e += 2) { body(e); body(e + 1); }
    if (e < end) body(e);

    if (RELU) {
#pragma unroll
        for (int i = 0; i < 8; ++i) acc[i] = fmaxf(acc[i], 0.f);
    }
    uint4 o;
    u32* ov = reinterpret_cast<u32*>(&o);
#pragma unroll
    for (int q = 0; q < 4; ++q) ov[q] = pk2(acc[q * 2], acc[q * 2 + 1]);
    reinterpret_cast<uint4*>(Hout)[(size_t)node * 16 + lane] = o;
}

// ------------- classifier: G[M,16] = Ah[M,128](fp16) @ Wc + bc -------------

__global__ void k_cls_h(const u32* __restrict__ Ah, const float* __restrict__ Wc,
                        const float* __restrict__ bc, float* __restrict__ G, int M) {
    __shared__ float sa[64][132];
    __shared__ float4 sw4[512];
    int tid  = threadIdx.x;
    int row0 = blockIdx.x * 64;

    for (int idx = tid; idx < 512; idx += 256)
        sw4[idx] = reinterpret_cast<const float4*>(Wc)[idx];

    const uint4* A4 = reinterpret_cast<const uint4*>(Ah);
    for (int idx = tid; idx < 64 * 16; idx += 256) {
        int r = idx >> 4, c = idx & 15;
        int gr = row0 + r;
        uint4 v = (gr < M) ? A4[(size_t)gr * 16 + c]
                           : make_uint4(0u, 0u, 0u, 0u);
        float* dst = &sa[r][c * 8];
        const u32* vv = reinterpret_cast<const u32*>(&v);
#pragma unroll
        for (int q = 0; q < 4; ++q) {
            float2 f = upk(vv[q]);
            dst[q * 2 + 0] = f.x;
            dst[q * 2 + 1] = f.y;
        }
    }
    __syncthreads();

    int tc = tid & 3;
    int tr = tid >> 2;
    float4 acc = make_float4(0.f, 0.f, 0.f, 0.f);
    for (int k4 = 0; k4 < 32; ++k4) {
        float4 a = *reinterpret_cast<const float4*>(&sa[tr][k4 * 4]);
        const float* af = reinterpret_cast<const float*>(&a);
#pragma unroll
        for (int kk = 0; kk < 4; ++kk) {
            float4 wv = sw4[(k4 * 4 + kk) * 4 + tc];
            float av = af[kk];
            acc.x += av * wv.x; acc.y += av * wv.y;
            acc.z += av * wv.z; acc.w += av * wv.w;
        }
    }
    int r = row0 + tr;
    if (r < M) {
        float4 bb = reinterpret_cast<const float4*>(bc)[tc];
        acc.x += bb.x; acc.y += bb.y; acc.z += bb.z; acc.w += bb.w;
        reinterpret_cast<float4*>(G)[(size_t)r * 4 + tc] = acc;
    }
}

// ---- final hop at width 16, fp32 ----

__global__ void k_prop16(const float* __restrict__ Gin, float* __restrict__ Out,
                         const int* __restrict__ rp, const int2* __restrict__ ew,
                         int n) {
    int g    = blockIdx.x * 64 + (threadIdx.x >> 2);
    int lane = threadIdx.x & 3;
    if (g >= n) return;
    int beg = rp[g], end = rp[g + 1];
    const float4* G4 = reinterpret_cast<const float4*>(Gin);
    float ax = 0.f, ay = 0.f, az = 0.f, aw = 0.f;
    for (int e = beg; e < end; ++e) {
        int2 p   = ew[e];
        float ww = __int_as_float(p.y);
        float4 hv = G4[(size_t)p.x * 4 + lane];
        ax += ww * hv.x; ay += ww * hv.y; az += ww * hv.z; aw += ww * hv.w;
    }
    reinterpret_cast<float4*>(Out)[(size_t)g * 4 + lane] = make_float4(ax, ay, az, aw);
}

// ---------------- host launch ----------------

extern "C" void kernel_launch(void* const* d_in, const int* in_sizes, int n_in,
                              void* d_out, int out_size, void* d_ws, size_t ws_size,
                              hipStream_t stream) {
    const float* x  = (const float*)d_in[0];
    const float* W1 = (const float*)d_in[1];
    const float* b1 = (const float*)d_in[2];
    const float* W2 = (const float*)d_in[3];
    const float* b2 = (const float*)d_in[4];
    const float* Wc = (const float*)d_in[5];
    const float* bc = (const float*)d_in[6];
    const int*   ei = (const int*)d_in[7];
    const int* srcp = ei;
    const int* dstp = ei + NEDGES;
    float* out = (float*)d_out;

    char* p = (char*)d_ws;
    auto alloc = [&](size_t bytes) -> char* {
        char* r = p;
        p += (bytes + 255) & ~(size_t)255;
        return r;
    };
    int*   deg    = (int*)  alloc(NNODES * 4);
    float* dinv   = (float*)alloc(NNODES * 4);
    int*   rp     = (int*)  alloc((NNODES + 1) * 4);
    int*   cursor = (int*)  alloc(NNODES * 4);
    int*   bsums  = (int*)  alloc(256 * 4);
    int2*  ew     = (int2*) alloc((size_t)(NEDGES + NNODES) * 8);
    f16*   xh     = (f16*)  alloc((size_t)MPAD * IN_F * 2);    // padded fp16 x
    f16*   W1t    = (f16*)  alloc((size_t)HID_F * IN_F * 2);   // W1^T fp16
    f16*   W2t    = (f16*)  alloc((size_t)HID_F * HID_F * 2);  // W2^T fp16
    f16*   H0h    = (f16*)  alloc((size_t)MPAD * HID_F * 2);   // gemm1 out (padded)
    u32*   Hh0    = (u32*)  alloc((size_t)NNODES * HID_F * 2);
    u32*   Hh1    = (u32*)  alloc((size_t)NNODES * HID_F * 2);
    float* G      = (float*)alloc((size_t)NNODES * OUT_F * 4);

    const int T = 256;
    auto nb = [](int n, int t) { return (n + t - 1) / t; };

    // graph norm + CSR build (+ per-node wave sort)
    k_init_deg<<<nb(NNODES, T), T, 0, stream>>>(deg, NNODES);
    k_count<<<nb(NEDGES, T), T, 0, stream>>>(dstp, deg, NEDGES);
    k_dinv<<<nb(NNODES, T), T, 0, stream>>>(deg, dinv, NNODES);
    int NB = nb(NNODES, 256);
    k_scan1<<<NB, 256, 0, stream>>>(deg, bsums, NNODES);
    k_scan2<<<1, 1, 0, stream>>>(bsums, NB, rp, NNODES);
    k_scan3<<<NB, 256, 0, stream>>>(deg, bsums, rp, cursor, NNODES);
    k_scatter<<<nb(NEDGES + NNODES, T), T, 0, stream>>>(srcp, dstp, dinv, cursor,
                                                        ew, NEDGES, NNODES);
    k_sortwave<<<nb(NNODES, 4), 256, 0, stream>>>(rp, ew, NNODES);

    // fp16 casts (overlap-friendly small kernels)
    k_cast_x<<<1024, 256, 0, stream>>>(x, xh, NNODES * IN_F);
    k_cast_wt<IN_F,  HID_F><<<nb(IN_F * HID_F, T), T, 0, stream>>>(W1, W1t);
    k_cast_wt<HID_F, HID_F><<<nb(HID_F * HID_F, T), T, 0, stream>>>(W2, W2t);

    // dense part on matrix cores: gemm1 f16->f16(relu), gemm2 f16->f16
    int GB = MPAD / 64;
    k_gemm_mfma<IN_F,  true ><<<GB, 256, 0, stream>>>(xh,  W1t, b1, H0h, NNODES);
    k_gemm_mfma<HID_F, false><<<GB, 256, 0, stream>>>(H0h, W2t, b2, (f16*)Hh0, NNODES);

    // 30 hops at width 128 in fp16, relu fused into last hop
    u32* cur = Hh0;
    u32* nxt = Hh1;
    int PB = nb(NNODES, 16);
    for (int i = 0; i < HOPS; ++i) {
        if (i == HOPS - 1)
            k_proph<true ><<<PB, 256, 0, stream>>>(cur, nxt, rp, ew, NNODES);
        else
            k_proph<false><<<PB, 256, 0, stream>>>(cur, nxt, rp, ew, NNODES);
        u32* t = cur; cur = nxt; nxt = t;
    }

    // classifier + final hop at width 16
    k_cls_h<<<nb(NNODES, 64), 256, 0, stream>>>(cur, Wc, bc, G, NNODES);
    k_prop16<<<nb(NNODES, 64), 256, 0, stream>>>(G, out, rp, ew, NNODES);
}